// Round 3
// baseline (3219.988 us; speedup 1.0000x reference)
//
#include <hip/hip_runtime.h>

#define BATCH 1024
#define NQ 16
#define DEPTH 8
#define NCLASS 10
#define RSQRT2 0.70710678118654752440f

#define SB() __builtin_amdgcn_sched_barrier(0)

// amplitude index: idx[15:12] = tid[9:6] (wave bits), idx[11:6] = tid[5:0] (lane bits),
// idx[5:0] = r (register index). qubit q lives at idx bit (15-q).
// q0..q3 -> wave bits 3..0 ; q4..q9 -> lane bits 5..0 ; q10..q15 -> local bits 5..0.

// ---------- local-bit gates (pure register, fully unrolled) ----------
template<int B>
__device__ __forceinline__ void ry_local(float st[64], float c, float s) {
#pragma unroll
  for (int r = 0; r < 64; ++r) {
    if ((r & (1 << B)) == 0) {
      float v0 = st[r], v1 = st[r | (1 << B)];
      st[r]            = fmaf(c, v0, -s * v1);
      st[r | (1 << B)] = fmaf(s, v0,  c * v1);
    }
  }
}

template<int CB, int TB>
__device__ __forceinline__ void cnot_local(float st[64]) {
#pragma unroll
  for (int r = 0; r < 64; ++r) {
    if (((r >> CB) & 1) == 1 && ((r >> TB) & 1) == 0) {
      float t = st[r];
      st[r] = st[r | (1 << TB)];
      st[r | (1 << TB)] = t;
    }
  }
}

// ctrl = thread-uniform predicate, target = local bit TB
template<int TB>
__device__ __forceinline__ void cnot_tlocal(float st[64], bool pred) {
#pragma unroll
  for (int r = 0; r < 64; ++r) {
    if (((r >> TB) & 1) == 0) {
      int r1 = r | (1 << TB);
      float v0 = st[r], v1 = st[r1];
      st[r]  = pred ? v1 : v0;
      st[r1] = pred ? v0 : v1;
    }
  }
}

// ---------- lane-bit gates (cross-lane shuffle, chunked to bound liveness) ----------
template<int L>
__device__ __forceinline__ void ry_lane(float st[64], float c, float s, int lane) {
  float ss = ((lane >> L) & 1) ? s : -s;
#pragma unroll
  for (int ch = 0; ch < 4; ++ch) {
#pragma unroll
    for (int k = 0; k < 16; ++k) {
      const int r = ch * 16 + k;
      float p = __shfl_xor(st[r], 1 << L, 64);
      st[r] = fmaf(ss, p, c * st[r]);
    }
    SB();  // cap outstanding shuffle temps at 16
  }
}

template<int L>
__device__ __forceinline__ void cnot_lane(float st[64], bool pred) {
#pragma unroll
  for (int ch = 0; ch < 4; ++ch) {
#pragma unroll
    for (int k = 0; k < 16; ++k) {
      const int r = ch * 16 + k;
      float p = __shfl_xor(st[r], 1 << L, 64);
      st[r] = pred ? p : st[r];
    }
    SB();
  }
}

// ---------- wave-bit gates (LDS exchange, 2 halves x 32 floats) ----------
// MODE 0 = RY (st = c*st + ss*partner), MODE 1 = CNOT (st = pred ? partner : st)
template<int W, int MODE>
__device__ __forceinline__ void wave_gate(float st[64], float* lds, int tid, int lane,
                                          float c, float ss, bool pred) {
  const int pt = tid ^ (64 << W);
#pragma unroll
  for (int h = 0; h < 2; ++h) {
    __syncthreads();   // protect previous LDS round / previous gate reads
#pragma unroll
    for (int j = 0; j < 8; ++j) {
      const int off = (4 * j + 4 * (lane & 7)) & 31;  // bank-spread rotation
      float4 v;
      v.x = st[h * 32 + 4 * j + 0];
      v.y = st[h * 32 + 4 * j + 1];
      v.z = st[h * 32 + 4 * j + 2];
      v.w = st[h * 32 + 4 * j + 3];
      *reinterpret_cast<float4*>(&lds[tid * 32 + off]) = v;
    }
    SB();
    __syncthreads();
#pragma unroll
    for (int j = 0; j < 8; ++j) {
      const int off = (4 * j + 4 * (lane & 7)) & 31;
      float4 p = *reinterpret_cast<const float4*>(&lds[pt * 32 + off]);
      if (MODE == 0) {
        st[h*32+4*j+0] = fmaf(ss, p.x, c * st[h*32+4*j+0]);
        st[h*32+4*j+1] = fmaf(ss, p.y, c * st[h*32+4*j+1]);
        st[h*32+4*j+2] = fmaf(ss, p.z, c * st[h*32+4*j+2]);
        st[h*32+4*j+3] = fmaf(ss, p.w, c * st[h*32+4*j+3]);
      } else {
        st[h*32+4*j+0] = pred ? p.x : st[h*32+4*j+0];
        st[h*32+4*j+1] = pred ? p.y : st[h*32+4*j+1];
        st[h*32+4*j+2] = pred ? p.z : st[h*32+4*j+2];
        st[h*32+4*j+3] = pred ? p.w : st[h*32+4*j+3];
      }
      SB();  // cap live staged float4s
    }
  }
}

template<int W>
__device__ __forceinline__ void ry_wave(float st[64], float* lds, int tid, int lane,
                                        float c, float s) {
  float ss = ((tid >> (6 + W)) & 1) ? s : -s;
  wave_gate<W, 0>(st, lds, tid, lane, c, ss, false);
}

template<int W>
__device__ __forceinline__ void cnot_wave(float st[64], float* lds, int tid, int lane, bool pred) {
  wave_gate<W, 1>(st, lds, tid, lane, 0.f, 0.f, pred);
}

__global__ __launch_bounds__(1024)
__attribute__((amdgpu_waves_per_eu(4, 4)))   // pin 4 waves/EU -> 128-VGPR cap, no 8-wave spill target
void vqc_kernel(const float* __restrict__ x,
                const float* __restrict__ w,
                float* __restrict__ out) {
  extern __shared__ float lds[];  // 1024*32 floats = 128 KB
  const int tid  = (int)threadIdx.x;
  const int lane = tid & 63;
  const int b    = (int)blockIdx.x;

  float st[64];

  // ---------- encoding: H + RY(x_q) is a product state ----------
  {
    float T = 1.0f;
#pragma unroll
    for (int q = 0; q <= 9; ++q) {  // thread-level qubits: tid bit (9-q)
      float th = 0.5f * x[b * NQ + q];
      float c = __cosf(th), s = __sinf(th);
      float f0 = (c - s) * RSQRT2;
      float f1 = (c + s) * RSQRT2;
      T *= ((tid >> (9 - q)) & 1) ? f1 : f0;
    }
    st[0] = T;
#pragma unroll
    for (int p = 0; p < 6; ++p) {   // local qubit q = 15-p at local bit p
      float th = 0.5f * x[b * NQ + (15 - p)];
      float c = __cosf(th), s = __sinf(th);
      float f0 = (c - s) * RSQRT2;
      float f1 = (c + s) * RSQRT2;
#pragma unroll
      for (int k = 0; k < 64; ++k) {
        if (k < (1 << p)) {
          float v = st[k];
          st[k]            = v * f0;
          st[k + (1 << p)] = v * f1;
        }
      }
    }
  }
  SB();

  // ---------- depth loop (kept rolled to bound code size) ----------
#pragma clang loop unroll(disable)
  for (int d = 0; d < DEPTH; ++d) {
    const float* wrow = w + d * NQ;

    // CNOT evens: (0,1)(2,3)(4,5)(6,7)(8,9)(10,11)(12,13)(14,15)
    cnot_wave<2>(st, lds, tid, lane, ((tid >> 9) & 1) != 0);  SB();  // (0,1)
    cnot_wave<0>(st, lds, tid, lane, ((tid >> 7) & 1) != 0);  SB();  // (2,3)
    cnot_lane<4>(st, ((lane >> 5) & 1) != 0);                 SB();  // (4,5)
    cnot_lane<2>(st, ((lane >> 3) & 1) != 0);                 SB();  // (6,7)
    cnot_lane<0>(st, ((lane >> 1) & 1) != 0);                 SB();  // (8,9)
    cnot_local<5, 4>(st);                                     SB();  // (10,11)
    cnot_local<3, 2>(st);                                     SB();  // (12,13)
    cnot_local<1, 0>(st);                                     SB();  // (14,15)

    // CNOT odds: (1,2)(3,4)(5,6)(7,8)(9,10)(11,12)(13,14)
    cnot_wave<1>(st, lds, tid, lane, ((tid >> 8) & 1) != 0);  SB();  // (1,2)
    cnot_lane<5>(st, ((tid >> 6) & 1) != 0);                  SB();  // (3,4)
    cnot_lane<3>(st, ((lane >> 4) & 1) != 0);                 SB();  // (5,6)
    cnot_lane<1>(st, ((lane >> 2) & 1) != 0);                 SB();  // (7,8)
    cnot_tlocal<5>(st, (lane & 1) != 0);                      SB();  // (9,10)
    cnot_local<4, 3>(st);                                     SB();  // (11,12)
    cnot_local<2, 1>(st);                                     SB();  // (13,14)

    // RY layer: lane + local first (short c/s liveness), wave last
    float th, c, s;
#define RYCS(q) th = 0.5f * wrow[q]; c = __cosf(th); s = __sinf(th);
    RYCS(4)  ry_lane<5>(st, c, s, lane);   SB();
    RYCS(5)  ry_lane<4>(st, c, s, lane);   SB();
    RYCS(6)  ry_lane<3>(st, c, s, lane);   SB();
    RYCS(7)  ry_lane<2>(st, c, s, lane);   SB();
    RYCS(8)  ry_lane<1>(st, c, s, lane);   SB();
    RYCS(9)  ry_lane<0>(st, c, s, lane);   SB();
    RYCS(10) ry_local<5>(st, c, s);        SB();
    RYCS(11) ry_local<4>(st, c, s);        SB();
    RYCS(12) ry_local<3>(st, c, s);        SB();
    RYCS(13) ry_local<2>(st, c, s);        SB();
    RYCS(14) ry_local<1>(st, c, s);        SB();
    RYCS(15) ry_local<0>(st, c, s);        SB();
    RYCS(0)  ry_wave<3>(st, lds, tid, lane, c, s);  SB();
    RYCS(1)  ry_wave<2>(st, lds, tid, lane, c, s);  SB();
    RYCS(2)  ry_wave<1>(st, lds, tid, lane, c, s);  SB();
    RYCS(3)  ry_wave<0>(st, lds, tid, lane, c, s);  SB();
#undef RYCS
  }

  // ---------- measurement: <Z_q>, q = 0..9 (all thread-level bits) ----------
  float tot = 0.f;
#pragma unroll
  for (int r = 0; r < 64; ++r) tot = fmaf(st[r], st[r], tot);

  // 7 wave reductions: [0] unsigned total (for wave-bit classes 0..3),
  // [1..6] lane-bit-signed totals for classes 4..9 (sign bit: lane bit 9-q)
  float red[7];
  red[0] = tot;
#pragma unroll
  for (int q = 4; q <= 9; ++q)
    red[q - 3] = (((lane >> (9 - q)) & 1) != 0) ? -tot : tot;
#pragma unroll
  for (int i = 0; i < 7; ++i) {
#pragma unroll
    for (int m = 1; m < 64; m <<= 1)
      red[i] += __shfl_xor(red[i], m, 64);
  }

  __syncthreads();  // done with gate LDS usage
  if (lane == 0) {
    const int wv = tid >> 6;
#pragma unroll
    for (int i = 0; i < 7; ++i) lds[wv * 8 + i] = red[i];
  }
  __syncthreads();

  if (tid < NCLASS) {
    float acc = 0.f;
    if (tid < 4) {  // class qubit q=tid on wave bit (3-tid)
#pragma unroll
      for (int wv = 0; wv < 16; ++wv) {
        float v = lds[wv * 8];
        acc += (((wv >> (3 - tid)) & 1) != 0) ? -v : v;
      }
    } else {        // class qubit q=tid, signed partial at red[tid-3]
#pragma unroll
      for (int wv = 0; wv < 16; ++wv) acc += lds[wv * 8 + (tid - 3)];
    }
    out[b * NCLASS + tid] = acc;
  }
}

extern "C" void kernel_launch(void* const* d_in, const int* in_sizes, int n_in,
                              void* d_out, int out_size, void* d_ws, size_t ws_size,
                              hipStream_t stream) {
  (void)in_sizes; (void)n_in; (void)d_ws; (void)ws_size; (void)out_size;
  const float* x = (const float*)d_in[0];
  const float* w = (const float*)d_in[1];
  float* out = (float*)d_out;

  // 128 KB dynamic LDS (gfx950 has 160 KB/CU) — opt in every call (idempotent).
  hipFuncSetAttribute(reinterpret_cast<const void*>(vqc_kernel),
                      hipFuncAttributeMaxDynamicSharedMemorySize, 131072);

  vqc_kernel<<<BATCH, 1024, 131072, stream>>>(x, w, out);
}

// Round 7
// 1798.831 us; speedup vs baseline: 1.7900x; 1.7900x over previous
//
#include <hip/hip_runtime.h>

#define BATCH 1024
#define NQ 16
#define DEPTH 8
#define NCLASS 10
#define RSQRT2 0.70710678118654752440f
#define SB() __builtin_amdgcn_sched_barrier(0)

// amplitude index: idx[15:12] = tid[9:6] (wave bits), idx[11:6] = tid[5:0] (lane bits),
// idx[5:0] = local. qubit q lives at idx bit (15-q).
// q0..q3 -> wave bits 3..0 ; q4..q9 -> lane bits 5..0 ; q10..q15 -> local bits 5..0.
// Local 64 amps = 16 NAMED float4 vars: A{n}, n = local[5:2]; component = local[1:0]
// (x,y,z,w). Named SSA values -> no alloca -> scratch structurally impossible.

// ---------- value-semantic gate helpers ----------
__device__ __forceinline__ float4 ryc4(float4 v, float4 p, float c, float ss) {
  float4 r;
  r.x = fmaf(ss, p.x, c * v.x);
  r.y = fmaf(ss, p.y, c * v.y);
  r.z = fmaf(ss, p.z, c * v.z);
  r.w = fmaf(ss, p.w, c * v.w);
  return r;
}
__device__ __forceinline__ float4 cxc4(float4 v, float4 p, bool pred) {
  float4 r;
  r.x = pred ? p.x : v.x;
  r.y = pred ? p.y : v.y;
  r.z = pred ? p.z : v.z;
  r.w = pred ? p.w : v.w;
  return r;
}
template<int L>
__device__ __forceinline__ float4 lry4(float4 a, float c, float ss) {
  float4 r;
  r.x = fmaf(ss, __shfl_xor(a.x, 1 << L, 64), c * a.x);
  r.y = fmaf(ss, __shfl_xor(a.y, 1 << L, 64), c * a.y);
  r.z = fmaf(ss, __shfl_xor(a.z, 1 << L, 64), c * a.z);
  r.w = fmaf(ss, __shfl_xor(a.w, 1 << L, 64), c * a.w);
  return r;
}
template<int L>
__device__ __forceinline__ float4 lcx4(float4 a, bool pred) {
  // shuffle computed unconditionally (convergent), then per-lane select
  float px = __shfl_xor(a.x, 1 << L, 64);
  float py = __shfl_xor(a.y, 1 << L, 64);
  float pz = __shfl_xor(a.z, 1 << L, 64);
  float pw = __shfl_xor(a.w, 1 << L, 64);
  float4 r;
  r.x = pred ? px : a.x;
  r.y = pred ? py : a.y;
  r.z = pred ? pz : a.z;
  r.w = pred ? pw : a.w;
  return r;
}

// ---------- local-gate macros over named vars ----------
#define PRY(a, b)  { float _t0 = (a), _t1 = (b); (a) = fmaf(c, _t0, -s * _t1); (b) = fmaf(s, _t0, c * _t1); }
#define PRY4(A, B) PRY(A.x, B.x) PRY(A.y, B.y) PRY(A.z, B.z) PRY(A.w, B.w)
#define SW4(A, B)  { float4 _t = (A); (A) = (B); (B) = _t; }
#define CSW1(a, b) { float _ta = (a), _tb = (b); (a) = pred ? _tb : _ta; (b) = pred ? _ta : _tb; }
#define CSW4(A, B) CSW1(A.x, B.x) CSW1(A.y, B.y) CSW1(A.z, B.z) CSW1(A.w, B.w)
#define SWZW(A)    { float _t = (A).z; (A).z = (A).w; (A).w = _t; }
#define SWXZYW(A)  { float _t = (A).x; (A).x = (A).z; (A).z = _t; _t = (A).y; (A).y = (A).w; (A).w = _t; }

#define LOC_RY(Q, PAIRS) { float th = 0.5f * wrow[Q]; float c = __cosf(th), s = __sinf(th); PAIRS }

// ---------- lane-gate macros (chunked: 4 vars = 16 shuffles in flight) ----------
#define LANE_RY(L, Q) { float th = 0.5f * wrow[Q]; float c = __cosf(th), s = __sinf(th); \
  const float ss = ((lane >> (L)) & 1) ? s : -s; \
  A0  = lry4<L>(A0,  c, ss); A1  = lry4<L>(A1,  c, ss); A2  = lry4<L>(A2,  c, ss); A3  = lry4<L>(A3,  c, ss); SB(); \
  A4  = lry4<L>(A4,  c, ss); A5  = lry4<L>(A5,  c, ss); A6  = lry4<L>(A6,  c, ss); A7  = lry4<L>(A7,  c, ss); SB(); \
  A8  = lry4<L>(A8,  c, ss); A9  = lry4<L>(A9,  c, ss); A10 = lry4<L>(A10, c, ss); A11 = lry4<L>(A11, c, ss); SB(); \
  A12 = lry4<L>(A12, c, ss); A13 = lry4<L>(A13, c, ss); A14 = lry4<L>(A14, c, ss); A15 = lry4<L>(A15, c, ss); SB(); }

#define LANE_CX(L, PRED) { const bool pred = (PRED); \
  A0  = lcx4<L>(A0,  pred); A1  = lcx4<L>(A1,  pred); A2  = lcx4<L>(A2,  pred); A3  = lcx4<L>(A3,  pred); SB(); \
  A4  = lcx4<L>(A4,  pred); A5  = lcx4<L>(A5,  pred); A6  = lcx4<L>(A6,  pred); A7  = lcx4<L>(A7,  pred); SB(); \
  A8  = lcx4<L>(A8,  pred); A9  = lcx4<L>(A9,  pred); A10 = lcx4<L>(A10, pred); A11 = lcx4<L>(A11, pred); SB(); \
  A12 = lcx4<L>(A12, pred); A13 = lcx4<L>(A13, pred); A14 = lcx4<L>(A14, pred); A15 = lcx4<L>(A15, pred); SB(); }

// ---------- wave-gate macros (LDS exchange, 2 halves x 8 float4) ----------
// partner thread differs in tid bit (6+W); same lane -> same rotation rb.
#define WSTORE_LO() \
  l4[tb+((0+rb)&7)] = A0; l4[tb+((1+rb)&7)] = A1; l4[tb+((2+rb)&7)] = A2; l4[tb+((3+rb)&7)] = A3; \
  l4[tb+((4+rb)&7)] = A4; l4[tb+((5+rb)&7)] = A5; l4[tb+((6+rb)&7)] = A6; l4[tb+((7+rb)&7)] = A7;
#define WSTORE_HI() \
  l4[tb+((0+rb)&7)] = A8;  l4[tb+((1+rb)&7)] = A9;  l4[tb+((2+rb)&7)] = A10; l4[tb+((3+rb)&7)] = A11; \
  l4[tb+((4+rb)&7)] = A12; l4[tb+((5+rb)&7)] = A13; l4[tb+((6+rb)&7)] = A14; l4[tb+((7+rb)&7)] = A15;

#define WGATE_RY(W, Q) { \
  float th = 0.5f * wrow[Q]; float c = __cosf(th), s = __sinf(th); \
  const float ss = ((tid >> (6 + (W))) & 1) ? s : -s; \
  const int tb = tid * 8, pb = (tid ^ (64 << (W))) * 8, rb = lane & 7; \
  __syncthreads(); \
  WSTORE_LO() \
  __syncthreads(); \
  A0 = ryc4(A0, l4[pb+((0+rb)&7)], c, ss); A1 = ryc4(A1, l4[pb+((1+rb)&7)], c, ss); \
  A2 = ryc4(A2, l4[pb+((2+rb)&7)], c, ss); A3 = ryc4(A3, l4[pb+((3+rb)&7)], c, ss); \
  A4 = ryc4(A4, l4[pb+((4+rb)&7)], c, ss); A5 = ryc4(A5, l4[pb+((5+rb)&7)], c, ss); \
  A6 = ryc4(A6, l4[pb+((6+rb)&7)], c, ss); A7 = ryc4(A7, l4[pb+((7+rb)&7)], c, ss); \
  SB(); \
  __syncthreads(); \
  WSTORE_HI() \
  __syncthreads(); \
  A8  = ryc4(A8,  l4[pb+((0+rb)&7)], c, ss); A9  = ryc4(A9,  l4[pb+((1+rb)&7)], c, ss); \
  A10 = ryc4(A10, l4[pb+((2+rb)&7)], c, ss); A11 = ryc4(A11, l4[pb+((3+rb)&7)], c, ss); \
  A12 = ryc4(A12, l4[pb+((4+rb)&7)], c, ss); A13 = ryc4(A13, l4[pb+((5+rb)&7)], c, ss); \
  A14 = ryc4(A14, l4[pb+((6+rb)&7)], c, ss); A15 = ryc4(A15, l4[pb+((7+rb)&7)], c, ss); \
  SB(); }

#define WGATE_CX(W, PRED) { \
  const bool pred = (PRED); \
  const int tb = tid * 8, pb = (tid ^ (64 << (W))) * 8, rb = lane & 7; \
  __syncthreads(); \
  WSTORE_LO() \
  __syncthreads(); \
  A0 = cxc4(A0, l4[pb+((0+rb)&7)], pred); A1 = cxc4(A1, l4[pb+((1+rb)&7)], pred); \
  A2 = cxc4(A2, l4[pb+((2+rb)&7)], pred); A3 = cxc4(A3, l4[pb+((3+rb)&7)], pred); \
  A4 = cxc4(A4, l4[pb+((4+rb)&7)], pred); A5 = cxc4(A5, l4[pb+((5+rb)&7)], pred); \
  A6 = cxc4(A6, l4[pb+((6+rb)&7)], pred); A7 = cxc4(A7, l4[pb+((7+rb)&7)], pred); \
  SB(); \
  __syncthreads(); \
  WSTORE_HI() \
  __syncthreads(); \
  A8  = cxc4(A8,  l4[pb+((0+rb)&7)], pred); A9  = cxc4(A9,  l4[pb+((1+rb)&7)], pred); \
  A10 = cxc4(A10, l4[pb+((2+rb)&7)], pred); A11 = cxc4(A11, l4[pb+((3+rb)&7)], pred); \
  A12 = cxc4(A12, l4[pb+((4+rb)&7)], pred); A13 = cxc4(A13, l4[pb+((5+rb)&7)], pred); \
  A14 = cxc4(A14, l4[pb+((6+rb)&7)], pred); A15 = cxc4(A15, l4[pb+((7+rb)&7)], pred); \
  SB(); }

#define SQ4(A) tot = fmaf((A).x,(A).x,tot); tot = fmaf((A).y,(A).y,tot); \
               tot = fmaf((A).z,(A).z,tot); tot = fmaf((A).w,(A).w,tot);
#define RED(v) { v += __shfl_xor(v, 1, 64); v += __shfl_xor(v, 2, 64); v += __shfl_xor(v, 4, 64); \
                 v += __shfl_xor(v, 8, 64); v += __shfl_xor(v, 16, 64); v += __shfl_xor(v, 32, 64); }

__global__ void
__attribute__((amdgpu_flat_work_group_size(1024, 1024)))
__attribute__((amdgpu_waves_per_eu(4, 4)))
vqc_kernel(const float* __restrict__ x,
           const float* __restrict__ w,
           float* __restrict__ out) {
  extern __shared__ float lds[];          // 128 KB dynamic
  float4* l4 = (float4*)lds;
  const int tid  = (int)threadIdx.x;
  const int lane = tid & 63;
  const int b    = (int)blockIdx.x;

  float4 A0, A1, A2, A3, A4, A5, A6, A7, A8, A9, A10, A11, A12, A13, A14, A15;

  // ---------- encoding: H + RY(x_q) is a product state ----------
  {
    float T = 1.0f;
#pragma unroll
    for (int q = 0; q <= 9; ++q) {        // thread-level qubits: tid bit (9-q)
      float th = 0.5f * x[b * NQ + q];
      float c = __cosf(th), s = __sinf(th);
      float f0 = (c - s) * RSQRT2;
      float f1 = (c + s) * RSQRT2;
      T *= ((tid >> (9 - q)) & 1) ? f1 : f0;
    }
    float f0, f1, th, c, s;
#define ENC_CS(Q) th = 0.5f * x[b * NQ + (Q)]; c = __cosf(th); s = __sinf(th); \
                  f0 = (c - s) * RSQRT2; f1 = (c + s) * RSQRT2;
    ENC_CS(15)  A0.y = T * f1;    A0.x = T * f0;                      // local bit 0
    ENC_CS(14)  A0.z = A0.x * f1; A0.w = A0.y * f1;                   // local bit 1
                A0.x *= f0;       A0.y *= f0;
#define M4(D, S, F) (D).x = (S).x * (F); (D).y = (S).y * (F); (D).z = (S).z * (F); (D).w = (S).w * (F);
    ENC_CS(13)  M4(A1, A0, f1) M4(A0, A0, f0)                         // local bit 2
    ENC_CS(12)  M4(A2, A0, f1) M4(A3, A1, f1) M4(A0, A0, f0) M4(A1, A1, f0)   // bit 3
    ENC_CS(11)  M4(A4, A0, f1) M4(A5, A1, f1) M4(A6, A2, f1) M4(A7, A3, f1)   // bit 4
                M4(A0, A0, f0) M4(A1, A1, f0) M4(A2, A2, f0) M4(A3, A3, f0)
    ENC_CS(10)  M4(A8,  A0, f1) M4(A9,  A1, f1) M4(A10, A2, f1) M4(A11, A3, f1)  // bit 5
                M4(A12, A4, f1) M4(A13, A5, f1) M4(A14, A6, f1) M4(A15, A7, f1)
                M4(A0, A0, f0) M4(A1, A1, f0) M4(A2, A2, f0) M4(A3, A3, f0)
                M4(A4, A4, f0) M4(A5, A5, f0) M4(A6, A6, f0) M4(A7, A7, f0)
#undef ENC_CS
  }
  SB();

  // ---------- depth loop ----------
#pragma clang loop unroll(disable)
  for (int d = 0; d < DEPTH; ++d) {
    const float* wrow = w + d * NQ;

    // CNOT evens: (0,1)(2,3)(4,5)(6,7)(8,9)(10,11)(12,13)(14,15)
    WGATE_CX(2, ((tid >> 9) & 1) != 0)                         // (0,1)
    WGATE_CX(0, ((tid >> 7) & 1) != 0)                         // (2,3)
    LANE_CX(4, ((lane >> 5) & 1) != 0)                         // (4,5)
    LANE_CX(2, ((lane >> 3) & 1) != 0)                         // (6,7)
    LANE_CX(0, ((lane >> 1) & 1) != 0)                         // (8,9)
    SW4(A8, A12) SW4(A9, A13) SW4(A10, A14) SW4(A11, A15)      // (10,11): ctrl l5, tgt l4
    SW4(A2, A3)  SW4(A6, A7)  SW4(A10, A11) SW4(A14, A15)      // (12,13): ctrl l3, tgt l2
    SWZW(A0)  SWZW(A1)  SWZW(A2)  SWZW(A3)  SWZW(A4)  SWZW(A5)  // (14,15): ctrl l1, tgt l0
    SWZW(A6)  SWZW(A7)  SWZW(A8)  SWZW(A9)  SWZW(A10) SWZW(A11)
    SWZW(A12) SWZW(A13) SWZW(A14) SWZW(A15)

    // CNOT odds: (1,2)(3,4)(5,6)(7,8)(9,10)(11,12)(13,14)
    WGATE_CX(1, ((tid >> 8) & 1) != 0)                         // (1,2)
    LANE_CX(5, ((tid >> 6) & 1) != 0)                          // (3,4): ctrl wave b0
    LANE_CX(3, ((lane >> 4) & 1) != 0)                         // (5,6)
    LANE_CX(1, ((lane >> 2) & 1) != 0)                         // (7,8)
    { const bool pred = (lane & 1) != 0;                       // (9,10): ctrl lane b0, tgt l5
      CSW4(A0, A8)  CSW4(A1, A9)  CSW4(A2, A10) CSW4(A3, A11)
      CSW4(A4, A12) CSW4(A5, A13) CSW4(A6, A14) CSW4(A7, A15) }
    SW4(A4, A6)  SW4(A5, A7)  SW4(A12, A14) SW4(A13, A15)      // (11,12): ctrl l4, tgt l3
    SWXZYW(A1)  SWXZYW(A3)  SWXZYW(A5)  SWXZYW(A7)             // (13,14): ctrl l2, tgt l1
    SWXZYW(A9)  SWXZYW(A11) SWXZYW(A13) SWXZYW(A15)

    // RY layer: lane + local first, wave last
    LANE_RY(5, 4)
    LANE_RY(4, 5)
    LANE_RY(3, 6)
    LANE_RY(2, 7)
    LANE_RY(1, 8)
    LANE_RY(0, 9)
    LOC_RY(10, PRY4(A0,A8) PRY4(A1,A9) PRY4(A2,A10) PRY4(A3,A11)
               PRY4(A4,A12) PRY4(A5,A13) PRY4(A6,A14) PRY4(A7,A15))
    LOC_RY(11, PRY4(A0,A4) PRY4(A1,A5) PRY4(A2,A6) PRY4(A3,A7)
               PRY4(A8,A12) PRY4(A9,A13) PRY4(A10,A14) PRY4(A11,A15))
    LOC_RY(12, PRY4(A0,A2) PRY4(A1,A3) PRY4(A4,A6) PRY4(A5,A7)
               PRY4(A8,A10) PRY4(A9,A11) PRY4(A12,A14) PRY4(A13,A15))
    LOC_RY(13, PRY4(A0,A1) PRY4(A2,A3) PRY4(A4,A5) PRY4(A6,A7)
               PRY4(A8,A9) PRY4(A10,A11) PRY4(A12,A13) PRY4(A14,A15))
    LOC_RY(14, PRY(A0.x,A0.z) PRY(A0.y,A0.w) PRY(A1.x,A1.z) PRY(A1.y,A1.w)
               PRY(A2.x,A2.z) PRY(A2.y,A2.w) PRY(A3.x,A3.z) PRY(A3.y,A3.w)
               PRY(A4.x,A4.z) PRY(A4.y,A4.w) PRY(A5.x,A5.z) PRY(A5.y,A5.w)
               PRY(A6.x,A6.z) PRY(A6.y,A6.w) PRY(A7.x,A7.z) PRY(A7.y,A7.w)
               PRY(A8.x,A8.z) PRY(A8.y,A8.w) PRY(A9.x,A9.z) PRY(A9.y,A9.w)
               PRY(A10.x,A10.z) PRY(A10.y,A10.w) PRY(A11.x,A11.z) PRY(A11.y,A11.w)
               PRY(A12.x,A12.z) PRY(A12.y,A12.w) PRY(A13.x,A13.z) PRY(A13.y,A13.w)
               PRY(A14.x,A14.z) PRY(A14.y,A14.w) PRY(A15.x,A15.z) PRY(A15.y,A15.w))
    LOC_RY(15, PRY(A0.x,A0.y) PRY(A0.z,A0.w) PRY(A1.x,A1.y) PRY(A1.z,A1.w)
               PRY(A2.x,A2.y) PRY(A2.z,A2.w) PRY(A3.x,A3.y) PRY(A3.z,A3.w)
               PRY(A4.x,A4.y) PRY(A4.z,A4.w) PRY(A5.x,A5.y) PRY(A5.z,A5.w)
               PRY(A6.x,A6.y) PRY(A6.z,A6.w) PRY(A7.x,A7.y) PRY(A7.z,A7.w)
               PRY(A8.x,A8.y) PRY(A8.z,A8.w) PRY(A9.x,A9.y) PRY(A9.z,A9.w)
               PRY(A10.x,A10.y) PRY(A10.z,A10.w) PRY(A11.x,A11.y) PRY(A11.z,A11.w)
               PRY(A12.x,A12.y) PRY(A12.z,A12.w) PRY(A13.x,A13.y) PRY(A13.z,A13.w)
               PRY(A14.x,A14.y) PRY(A14.z,A14.w) PRY(A15.x,A15.y) PRY(A15.z,A15.w))
    WGATE_RY(3, 0)
    WGATE_RY(2, 1)
    WGATE_RY(1, 2)
    WGATE_RY(0, 3)
  }

  // ---------- measurement: <Z_q>, q = 0..9 ----------
  float tot = 0.f;
  SQ4(A0)  SQ4(A1)  SQ4(A2)  SQ4(A3)  SQ4(A4)  SQ4(A5)  SQ4(A6)  SQ4(A7)
  SQ4(A8)  SQ4(A9)  SQ4(A10) SQ4(A11) SQ4(A12) SQ4(A13) SQ4(A14) SQ4(A15)

  // named reduction scalars: [r0] unsigned total (wave-bit classes 0..3),
  // r1..r6 = lane-bit-signed totals for classes 4..9 (sign bit: lane bit 9-q)
  float r0 = tot;
  float r1 = ((lane >> 5) & 1) ? -tot : tot;
  float r2 = ((lane >> 4) & 1) ? -tot : tot;
  float r3 = ((lane >> 3) & 1) ? -tot : tot;
  float r4 = ((lane >> 2) & 1) ? -tot : tot;
  float r5 = ((lane >> 1) & 1) ? -tot : tot;
  float r6 = ( lane       & 1) ? -tot : tot;
  RED(r0) RED(r1) RED(r2) RED(r3) RED(r4) RED(r5) RED(r6)

  __syncthreads();  // done with gate LDS usage
  if (lane == 0) {
    const int base = (tid >> 6) * 8;
    lds[base + 0] = r0; lds[base + 1] = r1; lds[base + 2] = r2; lds[base + 3] = r3;
    lds[base + 4] = r4; lds[base + 5] = r5; lds[base + 6] = r6;
  }
  __syncthreads();

  if (tid < NCLASS) {
    float acc = 0.f;
    if (tid < 4) {  // class qubit q=tid on wave bit (3-tid)
#pragma unroll
      for (int wv = 0; wv < 16; ++wv) {
        float v = lds[wv * 8];
        acc += (((wv >> (3 - tid)) & 1) != 0) ? -v : v;
      }
    } else {        // class qubit q=tid, signed partial at slot (tid-3)
#pragma unroll
      for (int wv = 0; wv < 16; ++wv) acc += lds[wv * 8 + (tid - 3)];
    }
    out[b * NCLASS + tid] = acc;
  }
}

extern "C" void kernel_launch(void* const* d_in, const int* in_sizes, int n_in,
                              void* d_out, int out_size, void* d_ws, size_t ws_size,
                              hipStream_t stream) {
  (void)in_sizes; (void)n_in; (void)d_ws; (void)ws_size; (void)out_size;
  const float* x = (const float*)d_in[0];
  const float* w = (const float*)d_in[1];
  float* out = (float*)d_out;

  // 128 KB dynamic LDS (gfx950 has 160 KB/CU) — opt in every call (idempotent).
  hipFuncSetAttribute(reinterpret_cast<const void*>(vqc_kernel),
                      hipFuncAttributeMaxDynamicSharedMemorySize, 131072);

  vqc_kernel<<<BATCH, 1024, 131072, stream>>>(x, w, out);
}

// Round 8
// 1221.458 us; speedup vs baseline: 2.6362x; 1.4727x over previous
//
#include <hip/hip_runtime.h>

#define BATCH 1024
#define NQ 16
#define DEPTH 8
#define NCLASS 10
#define RSQRT2 0.70710678118654752440f
#define SB() __builtin_amdgcn_sched_barrier(0)

// amplitude index: idx[15:12] = tid[9:6] (wave bits), idx[11:6] = tid[5:0] (lane bits),
// idx[5:0] = local. qubit q lives at idx bit (15-q).
// q0..q3 -> wave bits ; q4..q9 -> lane bits 5..0 ; q10..q15 -> local bits 5..0.
// Local 64 amps = 16 NAMED float4 vars A0..A15: n = local[5:2], component = local[1:0].
// Per layer, the wave-qubit gate block is handled by TRANSPOSING idx[15:12]<->idx[5:2]
// (q0..q3 become local n-bits, q10..q13 become wave bits), applying the gates as
// register ops, and transposing back. Transpose = 2 half-staged LDS exchanges (b64).

// ---------- cross-lane helpers: DPP for xor1/xor2 (VALU pipe), else shfl ----------
__device__ __forceinline__ float dppx1(float v) {  // lane ^ 1 : quad_perm [1,0,3,2]
  return __int_as_float(__builtin_amdgcn_mov_dpp(__float_as_int(v), 0xB1, 0xF, 0xF, true));
}
__device__ __forceinline__ float dppx2(float v) {  // lane ^ 2 : quad_perm [2,3,0,1]
  return __int_as_float(__builtin_amdgcn_mov_dpp(__float_as_int(v), 0x4E, 0xF, 0xF, true));
}
template<int L>
__device__ __forceinline__ float sx(float v) {
  if constexpr (L == 0) return dppx1(v);
  else if constexpr (L == 1) return dppx2(v);
  else return __shfl_xor(v, 1 << L, 64);
}

// ---------- value-semantic gate helpers ----------
template<int L>
__device__ __forceinline__ float4 lry4(float4 a, float c, float ss) {
  float4 r;
  r.x = fmaf(ss, sx<L>(a.x), c * a.x);
  r.y = fmaf(ss, sx<L>(a.y), c * a.y);
  r.z = fmaf(ss, sx<L>(a.z), c * a.z);
  r.w = fmaf(ss, sx<L>(a.w), c * a.w);
  return r;
}
template<int L>
__device__ __forceinline__ float4 lcx4(float4 a, bool pred) {
  float px = sx<L>(a.x), py = sx<L>(a.y), pz = sx<L>(a.z), pw = sx<L>(a.w);
  float4 r;
  r.x = pred ? px : a.x;
  r.y = pred ? py : a.y;
  r.z = pred ? pz : a.z;
  r.w = pred ? pw : a.w;
  return r;
}

// ---------- local-gate macros over named vars ----------
#define PRY(a, b)  { float _t0 = (a), _t1 = (b); (a) = fmaf(c, _t0, -s * _t1); (b) = fmaf(s, _t0, c * _t1); }
#define PRY4(A, B) PRY(A.x, B.x) PRY(A.y, B.y) PRY(A.z, B.z) PRY(A.w, B.w)
#define SW4(A, B)  { float4 _t = (A); (A) = (B); (B) = _t; }
#define CSW1(a, b) { float _ta = (a), _tb = (b); (a) = pred ? _tb : _ta; (b) = pred ? _ta : _tb; }
#define CSW4(A, B) CSW1(A.x, B.x) CSW1(A.y, B.y) CSW1(A.z, B.z) CSW1(A.w, B.w)
#define SWZW(A)    { float _t = (A).z; (A).z = (A).w; (A).w = _t; }
#define SWXZYW(A)  { float _t = (A).x; (A).x = (A).z; (A).z = _t; _t = (A).y; (A).y = (A).w; (A).w = _t; }
#define X32(A)     { (A).x = __shfl_xor((A).x, 32, 64); (A).y = __shfl_xor((A).y, 32, 64); \
                     (A).z = __shfl_xor((A).z, 32, 64); (A).w = __shfl_xor((A).w, 32, 64); }

#define LOC_RY(Q, PAIRS) { float th = 0.5f * wrow[Q]; float c = __cosf(th), s = __sinf(th); PAIRS }

// ---------- lane-gate macros (chunked: 4 vars in flight, SB caps liveness) ----------
#define LANE_RY(L, Q) { float th = 0.5f * wrow[Q]; float c = __cosf(th), s = __sinf(th); \
  const float ss = ((lane >> (L)) & 1) ? s : -s; \
  A0  = lry4<L>(A0,  c, ss); A1  = lry4<L>(A1,  c, ss); A2  = lry4<L>(A2,  c, ss); A3  = lry4<L>(A3,  c, ss); SB(); \
  A4  = lry4<L>(A4,  c, ss); A5  = lry4<L>(A5,  c, ss); A6  = lry4<L>(A6,  c, ss); A7  = lry4<L>(A7,  c, ss); SB(); \
  A8  = lry4<L>(A8,  c, ss); A9  = lry4<L>(A9,  c, ss); A10 = lry4<L>(A10, c, ss); A11 = lry4<L>(A11, c, ss); SB(); \
  A12 = lry4<L>(A12, c, ss); A13 = lry4<L>(A13, c, ss); A14 = lry4<L>(A14, c, ss); A15 = lry4<L>(A15, c, ss); SB(); }

#define LANE_CX(L, PRED) { const bool pred = (PRED); \
  A0  = lcx4<L>(A0,  pred); A1  = lcx4<L>(A1,  pred); A2  = lcx4<L>(A2,  pred); A3  = lcx4<L>(A3,  pred); SB(); \
  A4  = lcx4<L>(A4,  pred); A5  = lcx4<L>(A5,  pred); A6  = lcx4<L>(A6,  pred); A7  = lcx4<L>(A7,  pred); SB(); \
  A8  = lcx4<L>(A8,  pred); A9  = lcx4<L>(A9,  pred); A10 = lcx4<L>(A10, pred); A11 = lcx4<L>(A11, pred); SB(); \
  A12 = lcx4<L>(A12, pred); A13 = lcx4<L>(A13, pred); A14 = lcx4<L>(A14, pred); A15 = lcx4<L>(A15, pred); SB(); }

// ---------- transpose idx[15:12] <-> idx[5:2] via LDS (2 component halves) ----------
// writer (h=tid>>6, lane) stages var A_j at l2[tid*16 + (j ^ (lane&15))];
// reader (w=tid>>6, lane) gets new A'_h = writer(h,lane)'s A_w:
//   l2[(h*64+lane)*16 + (w ^ (lane&15))] = l2[h*1024 + rbs].
#define TSTORE(CA, CB) \
  l2[tb2+( 0^rt)] = make_float2(A0.CA, A0.CB);  l2[tb2+( 1^rt)] = make_float2(A1.CA, A1.CB); \
  l2[tb2+( 2^rt)] = make_float2(A2.CA, A2.CB);  l2[tb2+( 3^rt)] = make_float2(A3.CA, A3.CB); \
  l2[tb2+( 4^rt)] = make_float2(A4.CA, A4.CB);  l2[tb2+( 5^rt)] = make_float2(A5.CA, A5.CB); \
  l2[tb2+( 6^rt)] = make_float2(A6.CA, A6.CB);  l2[tb2+( 7^rt)] = make_float2(A7.CA, A7.CB); \
  l2[tb2+( 8^rt)] = make_float2(A8.CA, A8.CB);  l2[tb2+( 9^rt)] = make_float2(A9.CA, A9.CB); \
  l2[tb2+(10^rt)] = make_float2(A10.CA,A10.CB); l2[tb2+(11^rt)] = make_float2(A11.CA,A11.CB); \
  l2[tb2+(12^rt)] = make_float2(A12.CA,A12.CB); l2[tb2+(13^rt)] = make_float2(A13.CA,A13.CB); \
  l2[tb2+(14^rt)] = make_float2(A14.CA,A14.CB); l2[tb2+(15^rt)] = make_float2(A15.CA,A15.CB);

#define TREAD(H0, CA, CB, V0, V1, V2, V3) { \
  float2 t0 = l2[(H0+0)*1024 + rbs]; float2 t1 = l2[(H0+1)*1024 + rbs]; \
  float2 t2 = l2[(H0+2)*1024 + rbs]; float2 t3 = l2[(H0+3)*1024 + rbs]; \
  V0.CA = t0.x; V0.CB = t0.y; V1.CA = t1.x; V1.CB = t1.y; \
  V2.CA = t2.x; V2.CB = t2.y; V3.CA = t3.x; V3.CB = t3.y; } SB();

#define TRANSPOSE() { \
  const int tb2 = tid << 4; const int rt = lane & 15; \
  const int rbs = (lane << 4) + ((tid >> 6) ^ rt); \
  __syncthreads(); \
  TSTORE(x, y) \
  __syncthreads(); \
  TREAD( 0, x, y, A0, A1, A2, A3)  TREAD( 4, x, y, A4, A5, A6, A7) \
  TREAD( 8, x, y, A8, A9, A10,A11) TREAD(12, x, y, A12,A13,A14,A15) \
  __syncthreads(); \
  TSTORE(z, w) \
  __syncthreads(); \
  TREAD( 0, z, w, A0, A1, A2, A3)  TREAD( 4, z, w, A4, A5, A6, A7) \
  TREAD( 8, z, w, A8, A9, A10,A11) TREAD(12, z, w, A12,A13,A14,A15) \
}

#define SQ4(A) tot = fmaf((A).x,(A).x,tot); tot = fmaf((A).y,(A).y,tot); \
               tot = fmaf((A).z,(A).z,tot); tot = fmaf((A).w,(A).w,tot);
#define RED(v) { v += __shfl_xor(v, 1, 64); v += __shfl_xor(v, 2, 64); v += __shfl_xor(v, 4, 64); \
                 v += __shfl_xor(v, 8, 64); v += __shfl_xor(v, 16, 64); v += __shfl_xor(v, 32, 64); }

__global__ void
__attribute__((amdgpu_flat_work_group_size(1024, 1024)))
__attribute__((amdgpu_waves_per_eu(4, 4)))
__attribute__((amdgpu_num_vgpr(128)))
vqc_kernel(const float* __restrict__ x,
           const float* __restrict__ w,
           float* __restrict__ out) {
  extern __shared__ float lds[];          // 128 KB dynamic
  float2* l2 = (float2*)lds;
  const int tid  = (int)threadIdx.x;
  const int lane = tid & 63;
  const int b    = (int)blockIdx.x;

  float4 A0, A1, A2, A3, A4, A5, A6, A7, A8, A9, A10, A11, A12, A13, A14, A15;

  // ---------- encoding: H + RY(x_q) is a product state ----------
  {
    float T = 1.0f;
#pragma unroll
    for (int q = 0; q <= 9; ++q) {        // thread-level qubits: tid bit (9-q)
      float th = 0.5f * x[b * NQ + q];
      float c = __cosf(th), s = __sinf(th);
      float f0 = (c - s) * RSQRT2;
      float f1 = (c + s) * RSQRT2;
      T *= ((tid >> (9 - q)) & 1) ? f1 : f0;
    }
    float f0, f1, th, c, s;
#define ENC_CS(Q) th = 0.5f * x[b * NQ + (Q)]; c = __cosf(th); s = __sinf(th); \
                  f0 = (c - s) * RSQRT2; f1 = (c + s) * RSQRT2;
    ENC_CS(15)  A0.y = T * f1;    A0.x = T * f0;                      // local bit 0
    ENC_CS(14)  A0.z = A0.x * f1; A0.w = A0.y * f1;                   // local bit 1
                A0.x *= f0;       A0.y *= f0;
#define M4(D, S, F) (D).x = (S).x * (F); (D).y = (S).y * (F); (D).z = (S).z * (F); (D).w = (S).w * (F);
    ENC_CS(13)  M4(A1, A0, f1) M4(A0, A0, f0)                         // local bit 2
    ENC_CS(12)  M4(A2, A0, f1) M4(A3, A1, f1) M4(A0, A0, f0) M4(A1, A1, f0)   // bit 3
    ENC_CS(11)  M4(A4, A0, f1) M4(A5, A1, f1) M4(A6, A2, f1) M4(A7, A3, f1)   // bit 4
                M4(A0, A0, f0) M4(A1, A1, f0) M4(A2, A2, f0) M4(A3, A3, f0)
    ENC_CS(10)  M4(A8,  A0, f1) M4(A9,  A1, f1) M4(A10, A2, f1) M4(A11, A3, f1)  // bit 5
                M4(A12, A4, f1) M4(A13, A5, f1) M4(A14, A6, f1) M4(A15, A7, f1)
                M4(A0, A0, f0) M4(A1, A1, f0) M4(A2, A2, f0) M4(A3, A3, f0)
                M4(A4, A4, f0) M4(A5, A5, f0) M4(A6, A6, f0) M4(A7, A7, f0)
#undef ENC_CS
  }
  SB();

  // ---------- depth loop ----------
#pragma clang loop unroll(disable)
  for (int d = 0; d < DEPTH; ++d) {
    const float* wrow = w + d * NQ;

    // ===== canonical phase: all gates NOT touching wave qubits q0..q3 =====
    // CX evens (4,5)(6,7)(8,9)(10,11)(12,13)(14,15)
    LANE_CX(4, ((lane >> 5) & 1) != 0)                         // (4,5)
    LANE_CX(2, ((lane >> 3) & 1) != 0)                         // (6,7)
    LANE_CX(0, ((lane >> 1) & 1) != 0)                         // (8,9)  [DPP]
    SW4(A8, A12) SW4(A9, A13) SW4(A10, A14) SW4(A11, A15)      // (10,11): ctrl n3, tgt n2
    SW4(A2, A3)  SW4(A6, A7)  SW4(A10, A11) SW4(A14, A15)      // (12,13): ctrl n1, tgt n0
    SWZW(A0)  SWZW(A1)  SWZW(A2)  SWZW(A3)  SWZW(A4)  SWZW(A5)  // (14,15): comp z<->w
    SWZW(A6)  SWZW(A7)  SWZW(A8)  SWZW(A9)  SWZW(A10) SWZW(A11)
    SWZW(A12) SWZW(A13) SWZW(A14) SWZW(A15)

    // CX odds (5,6)(7,8)(9,10)(11,12)(13,14)
    LANE_CX(3, ((lane >> 4) & 1) != 0)                         // (5,6)
    LANE_CX(1, ((lane >> 2) & 1) != 0)                         // (7,8)  [DPP]
    { const bool pred = (lane & 1) != 0;                       // (9,10): ctrl lane0, tgt n3
      CSW4(A0, A8)  CSW4(A1, A9)  CSW4(A2, A10) CSW4(A3, A11)
      CSW4(A4, A12) CSW4(A5, A13) CSW4(A6, A14) CSW4(A7, A15) }
    SW4(A4, A6)  SW4(A5, A7)  SW4(A12, A14) SW4(A13, A15)      // (11,12): ctrl n2, tgt n1
    SWXZYW(A1)  SWXZYW(A3)  SWXZYW(A5)  SWXZYW(A7)             // (13,14): ctrl n0, tgt comp1
    SWXZYW(A9)  SWXZYW(A11) SWXZYW(A13) SWXZYW(A15)

    // RY q5..q15 (q4 deferred until after CX(3,4))
    LANE_RY(4, 5)
    LANE_RY(3, 6)
    LANE_RY(2, 7)
    LANE_RY(1, 8)   // [DPP]
    LANE_RY(0, 9)   // [DPP]
    LOC_RY(10, PRY4(A0,A8) PRY4(A1,A9) PRY4(A2,A10) PRY4(A3,A11)
               PRY4(A4,A12) PRY4(A5,A13) PRY4(A6,A14) PRY4(A7,A15))
    LOC_RY(11, PRY4(A0,A4) PRY4(A1,A5) PRY4(A2,A6) PRY4(A3,A7)
               PRY4(A8,A12) PRY4(A9,A13) PRY4(A10,A14) PRY4(A11,A15))
    LOC_RY(12, PRY4(A0,A2) PRY4(A1,A3) PRY4(A4,A6) PRY4(A5,A7)
               PRY4(A8,A10) PRY4(A9,A11) PRY4(A12,A14) PRY4(A13,A15))
    LOC_RY(13, PRY4(A0,A1) PRY4(A2,A3) PRY4(A4,A5) PRY4(A6,A7)
               PRY4(A8,A9) PRY4(A10,A11) PRY4(A12,A13) PRY4(A14,A15))
    LOC_RY(14, PRY(A0.x,A0.z) PRY(A0.y,A0.w) PRY(A1.x,A1.z) PRY(A1.y,A1.w)
               PRY(A2.x,A2.z) PRY(A2.y,A2.w) PRY(A3.x,A3.z) PRY(A3.y,A3.w)
               PRY(A4.x,A4.z) PRY(A4.y,A4.w) PRY(A5.x,A5.z) PRY(A5.y,A5.w)
               PRY(A6.x,A6.z) PRY(A6.y,A6.w) PRY(A7.x,A7.z) PRY(A7.y,A7.w)
               PRY(A8.x,A8.z) PRY(A8.y,A8.w) PRY(A9.x,A9.z) PRY(A9.y,A9.w)
               PRY(A10.x,A10.z) PRY(A10.y,A10.w) PRY(A11.x,A11.z) PRY(A11.y,A11.w)
               PRY(A12.x,A12.z) PRY(A12.y,A12.w) PRY(A13.x,A13.z) PRY(A13.y,A13.w)
               PRY(A14.x,A14.z) PRY(A14.y,A14.w) PRY(A15.x,A15.z) PRY(A15.y,A15.w))
    LOC_RY(15, PRY(A0.x,A0.y) PRY(A0.z,A0.w) PRY(A1.x,A1.y) PRY(A1.z,A1.w)
               PRY(A2.x,A2.y) PRY(A2.z,A2.w) PRY(A3.x,A3.y) PRY(A3.z,A3.w)
               PRY(A4.x,A4.y) PRY(A4.z,A4.w) PRY(A5.x,A5.y) PRY(A5.z,A5.w)
               PRY(A6.x,A6.y) PRY(A6.z,A6.w) PRY(A7.x,A7.y) PRY(A7.z,A7.w)
               PRY(A8.x,A8.y) PRY(A8.z,A8.w) PRY(A9.x,A9.y) PRY(A9.z,A9.w)
               PRY(A10.x,A10.y) PRY(A10.z,A10.w) PRY(A11.x,A11.y) PRY(A11.z,A11.w)
               PRY(A12.x,A12.y) PRY(A12.z,A12.w) PRY(A13.x,A13.y) PRY(A13.z,A13.w)
               PRY(A14.x,A14.y) PRY(A14.z,A14.w) PRY(A15.x,A15.y) PRY(A15.z,A15.w))

    // ===== transposed phase: q0->n3, q1->n2, q2->n1, q3->n0 =====
    TRANSPOSE()
    SW4(A8, A12) SW4(A9, A13) SW4(A10, A14) SW4(A11, A15)      // CX(0,1): ctrl n3, tgt n2
    SW4(A2, A3)  SW4(A6, A7)  SW4(A10, A11) SW4(A14, A15)      // CX(2,3): ctrl n1, tgt n0
    SW4(A4, A6)  SW4(A5, A7)  SW4(A12, A14) SW4(A13, A15)      // CX(1,2): ctrl n2, tgt n1
    X32(A1) X32(A3) X32(A5) X32(A7)                            // CX(3,4): ctrl n0, tgt lane5
    X32(A9) X32(A11) X32(A13) X32(A15)
    LOC_RY(0, PRY4(A0,A8) PRY4(A1,A9) PRY4(A2,A10) PRY4(A3,A11)     // RY(0): n3
              PRY4(A4,A12) PRY4(A5,A13) PRY4(A6,A14) PRY4(A7,A15))
    LOC_RY(1, PRY4(A0,A4) PRY4(A1,A5) PRY4(A2,A6) PRY4(A3,A7)       // RY(1): n2
              PRY4(A8,A12) PRY4(A9,A13) PRY4(A10,A14) PRY4(A11,A15))
    LOC_RY(2, PRY4(A0,A2) PRY4(A1,A3) PRY4(A4,A6) PRY4(A5,A7)       // RY(2): n1
              PRY4(A8,A10) PRY4(A9,A11) PRY4(A12,A14) PRY4(A13,A15))
    LOC_RY(3, PRY4(A0,A1) PRY4(A2,A3) PRY4(A4,A5) PRY4(A6,A7)       // RY(3): n0
              PRY4(A8,A9) PRY4(A10,A11) PRY4(A12,A13) PRY4(A14,A15))
    LANE_RY(5, 4)                                              // RY(4): lane5 (after CX(3,4))
    TRANSPOSE()
  }

  // ---------- measurement: <Z_q>, q = 0..9 ----------
  float tot = 0.f;
  SQ4(A0)  SQ4(A1)  SQ4(A2)  SQ4(A3)  SQ4(A4)  SQ4(A5)  SQ4(A6)  SQ4(A7)
  SQ4(A8)  SQ4(A9)  SQ4(A10) SQ4(A11) SQ4(A12) SQ4(A13) SQ4(A14) SQ4(A15)

  // named reduction scalars: r0 unsigned total (wave-bit classes 0..3),
  // r1..r6 lane-bit-signed totals for classes 4..9 (sign bit: lane bit 9-q)
  float r0 = tot;
  float r1 = ((lane >> 5) & 1) ? -tot : tot;
  float r2 = ((lane >> 4) & 1) ? -tot : tot;
  float r3 = ((lane >> 3) & 1) ? -tot : tot;
  float r4 = ((lane >> 2) & 1) ? -tot : tot;
  float r5 = ((lane >> 1) & 1) ? -tot : tot;
  float r6 = ( lane       & 1) ? -tot : tot;
  RED(r0) RED(r1) RED(r2) RED(r3) RED(r4) RED(r5) RED(r6)

  __syncthreads();  // done with gate LDS usage
  if (lane == 0) {
    const int base = (tid >> 6) * 8;
    lds[base + 0] = r0; lds[base + 1] = r1; lds[base + 2] = r2; lds[base + 3] = r3;
    lds[base + 4] = r4; lds[base + 5] = r5; lds[base + 6] = r6;
  }
  __syncthreads();

  if (tid < NCLASS) {
    float acc = 0.f;
    if (tid < 4) {  // class qubit q=tid on wave bit (3-tid)
#pragma unroll
      for (int wv = 0; wv < 16; ++wv) {
        float v = lds[wv * 8];
        acc += (((wv >> (3 - tid)) & 1) != 0) ? -v : v;
      }
    } else {        // class qubit q=tid, signed partial at slot (tid-3)
#pragma unroll
      for (int wv = 0; wv < 16; ++wv) acc += lds[wv * 8 + (tid - 3)];
    }
    out[b * NCLASS + tid] = acc;
  }
}

extern "C" void kernel_launch(void* const* d_in, const int* in_sizes, int n_in,
                              void* d_out, int out_size, void* d_ws, size_t ws_size,
                              hipStream_t stream) {
  (void)in_sizes; (void)n_in; (void)d_ws; (void)ws_size; (void)out_size;
  const float* x = (const float*)d_in[0];
  const float* w = (const float*)d_in[1];
  float* out = (float*)d_out;

  // 128 KB dynamic LDS (gfx950 has 160 KB/CU) — opt in every call (idempotent).
  hipFuncSetAttribute(reinterpret_cast<const void*>(vqc_kernel),
                      hipFuncAttributeMaxDynamicSharedMemorySize, 131072);

  vqc_kernel<<<BATCH, 1024, 131072, stream>>>(x, w, out);
}

// Round 11
// 598.062 us; speedup vs baseline: 5.3840x; 2.0424x over previous
//
#include <hip/hip_runtime.h>
#include <hip/hip_fp16.h>

#define BATCH 1024
#define NQ 16
#define DEPTH 8
#define NCLASS 10
#define RSQRT2 0.70710678118654752440f
#define SB() __builtin_amdgcn_sched_barrier(0)

// amplitude index: idx[15:12]=wave bits (tid[9:6]), idx[11:6]=lane bits, idx[5:0]=local.
// qubit q <-> idx bit (15-q):  q0..3 wave, q4..9 lane bits 5..0, q10..15 local bits 5..0.
// PACKED f16 state: 32 __half2 per thread = 8 structs P0..P7 of 4 half2 each.
//   g = local[5:3] -> struct index (g2=local5=q10, g1=local4=q11, g0=local3=q12)
//   j = local[2:1] -> component x,y,z,w (j1=local2=q13, j0=local1=q14)
//   r = local[0]   -> half2 lane (q15)
// Gate math in f32 coefficients, state storage f16 (pk math, 2 amps/inst).

struct H4 { __half2 x, y, z, w; };

__device__ __forceinline__ float h2f(__half2 v) { return __builtin_bit_cast(float, v); }
__device__ __forceinline__ __half2 f2h(float v) { return __builtin_bit_cast(__half2, v); }

__device__ __forceinline__ float dppx1(float v) {  // lane ^ 1
  return __int_as_float(__builtin_amdgcn_mov_dpp(__float_as_int(v), 0xB1, 0xF, 0xF, true));
}
__device__ __forceinline__ float dppx2(float v) {  // lane ^ 2
  return __int_as_float(__builtin_amdgcn_mov_dpp(__float_as_int(v), 0x4E, 0xF, 0xF, true));
}
template<int L>
__device__ __forceinline__ float sxf(float v) {
  if constexpr (L == 0) return dppx1(v);
  else if constexpr (L == 1) return dppx2(v);
  else return __shfl_xor(v, 1 << L, 64);
}

// ---------- lane gates (cross-lane on packed 32-bit words) ----------
#define LRY1(L, H) __hfma2(SS2, f2h(sxf<L>(h2f(H))), __hmul2(C2, (H)))
#define LRYP(L, P) P.x = LRY1(L, P.x); P.y = LRY1(L, P.y); P.z = LRY1(L, P.z); P.w = LRY1(L, P.w);
#define LANE_RY(L, Q) { float th = 0.5f * wrow[Q]; float c = __cosf(th), s = __sinf(th); \
  const float ssv = ((lane >> (L)) & 1) ? s : -s; \
  const __half2 C2 = __float2half2_rn(c), SS2 = __float2half2_rn(ssv); \
  LRYP(L, P0) LRYP(L, P1) SB(); LRYP(L, P2) LRYP(L, P3) SB(); \
  LRYP(L, P4) LRYP(L, P5) SB(); LRYP(L, P6) LRYP(L, P7) SB(); }

#define LCX1(L, H) { float _a = h2f(H); float _p = sxf<L>(_a); (H) = f2h(pred ? _p : _a); }
#define LCXP(L, P) LCX1(L, P.x) LCX1(L, P.y) LCX1(L, P.z) LCX1(L, P.w)
#define LANE_CX(L, PRED) { const bool pred = (PRED); \
  LCXP(L, P0) LCXP(L, P1) SB(); LCXP(L, P2) LCXP(L, P3) SB(); \
  LCXP(L, P4) LCXP(L, P5) SB(); LCXP(L, P6) LCXP(L, P7) SB(); }

// ---------- local gates (pure register, packed) ----------
#define PRYH(A, B) { __half2 _t0 = (A), _t1 = (B); \
  (A) = __hfma2(NS2, _t1, __hmul2(C2, _t0)); \
  (B) = __hfma2(S2,  _t0, __hmul2(C2, _t1)); }
#define PRY4H(PA, PB) PRYH(PA.x, PB.x) PRYH(PA.y, PB.y) PRYH(PA.z, PB.z) PRYH(PA.w, PB.w)
#define LOC_RY(Q, BODY) { float th = 0.5f * wrow[Q]; float c = __cosf(th), s = __sinf(th); \
  const __half2 C2 = __float2half2_rn(c), S2 = __float2half2_rn(s), NS2 = __float2half2_rn(-s); \
  BODY }
// RY(15): within-half2 (target = r bit). lo' = c*lo - s*hi ; hi' = s*lo + c*hi
#define RY15S(H) { __half2 _t = __lowhigh2highlow(H); (H) = __hfma2(M2, _t, __hmul2(C2, (H))); }
#define RY15P(P) RY15S(P.x) RY15S(P.y) RY15S(P.z) RY15S(P.w)
#define LOC_RY15(Q) { float th = 0.5f * wrow[Q]; float c = __cosf(th), s = __sinf(th); \
  const __half2 C2 = __float2half2_rn(c); const __half2 M2 = __floats2half2_rn(-s, s); \
  RY15P(P0) RY15P(P1) RY15P(P2) RY15P(P3) RY15P(P4) RY15P(P5) RY15P(P6) RY15P(P7) }

#define SW4(A, B)   { H4 _t = (A); (A) = (B); (B) = _t; }
#define SWZW(P)     { __half2 _t = (P).z; (P).z = (P).w; (P).w = _t; }
#define SWXZYW(P)   { __half2 _t = (P).x; (P).x = (P).z; (P).z = _t; \
                      _t = (P).y; (P).y = (P).w; (P).w = _t; }
#define HSW(H)      (H) = __lowhigh2highlow(H);
#define CSWH(A, B)  { float _a = h2f(A), _b = h2f(B); (A) = f2h(pred ? _b : _a); (B) = f2h(pred ? _a : _b); }
#define CSWP(PA, PB) CSWH(PA.x, PB.x) CSWH(PA.y, PB.y) CSWH(PA.z, PB.z) CSWH(PA.w, PB.w)
#define X32C(H)     (H) = f2h(__shfl_xor(h2f(H), 32, 64));

// ---------- transpose idx[15:12] <-> idx[5:2] via LDS, ONE round (16 x 8B/thread) ----------
// word G = g*2+j1: {comp(j1,j0=0), comp(j1,j0=1)}. writer: l2[tid*16 + (G^rt)];
// reader: word G (new) from writer-wave G, slot (wv^rt):  l2[G*1024 + lane*16 + (wv^rt)].
#define TS(G, A, B) l2[tb + ((G) ^ rt)] = make_float2(h2f(A), h2f(B));
#define TR(G, A, B) { float2 _t = l2[(G) * 1024 + rb]; (A) = f2h(_t.x); (B) = f2h(_t.y); }
#define TRANSPOSE() { \
  const int tb = tid << 4; const int rt = lane & 15; \
  const int rb = (lane << 4) + ((tid >> 6) ^ rt); \
  __syncthreads(); \
  TS( 0, P0.x, P0.y) TS( 1, P0.z, P0.w) TS( 2, P1.x, P1.y) TS( 3, P1.z, P1.w) \
  TS( 4, P2.x, P2.y) TS( 5, P2.z, P2.w) TS( 6, P3.x, P3.y) TS( 7, P3.z, P3.w) \
  TS( 8, P4.x, P4.y) TS( 9, P4.z, P4.w) TS(10, P5.x, P5.y) TS(11, P5.z, P5.w) \
  TS(12, P6.x, P6.y) TS(13, P6.z, P6.w) TS(14, P7.x, P7.y) TS(15, P7.z, P7.w) \
  __syncthreads(); \
  TR( 0, P0.x, P0.y) TR( 1, P0.z, P0.w) TR( 2, P1.x, P1.y) TR( 3, P1.z, P1.w) SB(); \
  TR( 4, P2.x, P2.y) TR( 5, P2.z, P2.w) TR( 6, P3.x, P3.y) TR( 7, P3.z, P3.w) SB(); \
  TR( 8, P4.x, P4.y) TR( 9, P4.z, P4.w) TR(10, P5.x, P5.y) TR(11, P5.z, P5.w) SB(); \
  TR(12, P6.x, P6.y) TR(13, P6.z, P6.w) TR(14, P7.x, P7.y) TR(15, P7.z, P7.w) SB(); \
}

#define SQH(H) { float2 _f = __half22float2(H); tot = fmaf(_f.x, _f.x, tot); tot = fmaf(_f.y, _f.y, tot); }
#define SQP(P) SQH(P.x) SQH(P.y) SQH(P.z) SQH(P.w)
#define RED(v) { v += __shfl_xor(v, 1, 64); v += __shfl_xor(v, 2, 64); v += __shfl_xor(v, 4, 64); \
                 v += __shfl_xor(v, 8, 64); v += __shfl_xor(v, 16, 64); v += __shfl_xor(v, 32, 64); }

__global__ void
__attribute__((amdgpu_flat_work_group_size(1024, 1024)))
__attribute__((amdgpu_waves_per_eu(4, 4)))
vqc_kernel(const float* __restrict__ x,
           const float* __restrict__ w,
           float* __restrict__ out) {
  extern __shared__ float lds[];          // 128 KB dynamic
  float2* l2 = (float2*)lds;
  const int tid  = (int)threadIdx.x;
  const int lane = tid & 63;
  const int b    = (int)blockIdx.x;

  H4 P0, P1, P2, P3, P4, P5, P6, P7;

  // ---------- encoding (f32): H + RY(x_q) product state, then pack to f16 ----------
  {
    float T = 1.0f;
#pragma unroll
    for (int q = 0; q <= 9; ++q) {        // thread-level qubits: tid bit (9-q)
      float th = 0.5f * x[b * NQ + q];
      float c = __cosf(th), s = __sinf(th);
      float f0 = (c - s) * RSQRT2;
      float f1 = (c + s) * RSQRT2;
      T *= ((tid >> (9 - q)) & 1) ? f1 : f0;
    }
    float th, c, s, f0, f1;
#define ECS(Q) th = 0.5f * x[b * NQ + (Q)]; c = __cosf(th); s = __sinf(th); \
               f0 = (c - s) * RSQRT2; f1 = (c + s) * RSQRT2;
    ECS(10) const float f10a = f0, f10b = f1;
    ECS(11) const float f11a = f0, f11b = f1;
    ECS(12) const float f12a = f0, f12b = f1;
    ECS(13) const float f13a = f0, f13b = f1;
    ECS(14) const float f14a = f0, f14b = f1;
    ECS(15) const float f15a = f0, f15b = f1;
#undef ECS
    const float b0 = T * f10a * f11a * f12a, b1 = T * f10a * f11a * f12b;
    const float b2 = T * f10a * f11b * f12a, b3 = T * f10a * f11b * f12b;
    const float b4 = T * f10b * f11a * f12a, b5 = T * f10b * f11a * f12b;
    const float b6 = T * f10b * f11b * f12a, b7 = T * f10b * f11b * f12b;
#define PACK(v) __floats2half2_rn((v) * f15a, (v) * f15b)
#define SETP(P, bg) P.x = PACK((bg) * f13a * f14a); P.y = PACK((bg) * f13a * f14b); \
                    P.z = PACK((bg) * f13b * f14a); P.w = PACK((bg) * f13b * f14b);
    SETP(P0, b0) SETP(P1, b1) SETP(P2, b2) SETP(P3, b3)
    SETP(P4, b4) SETP(P5, b5) SETP(P6, b6) SETP(P7, b7)
#undef SETP
#undef PACK
  }
  SB();

  // ---------- depth loop ----------
#pragma clang loop unroll(disable)
  for (int d = 0; d < DEPTH; ++d) {
    const float* wrow = w + d * NQ;

    // ===== canonical phase: gates not touching q0..q3 =====
    // CX evens (4,5)(6,7)(8,9)(10,11)(12,13)(14,15)
    LANE_CX(4, ((lane >> 5) & 1) != 0)                    // (4,5)
    LANE_CX(2, ((lane >> 3) & 1) != 0)                    // (6,7)
    LANE_CX(0, ((lane >> 1) & 1) != 0)                    // (8,9) [DPP]
    SW4(P4, P6) SW4(P5, P7)                               // (10,11): ctrl g2, tgt g1
    SWXZYW(P1) SWXZYW(P3) SWXZYW(P5) SWXZYW(P7)           // (12,13): ctrl g0, tgt j1
    HSW(P0.y) HSW(P0.w) HSW(P1.y) HSW(P1.w)               // (14,15): ctrl j0, tgt r
    HSW(P2.y) HSW(P2.w) HSW(P3.y) HSW(P3.w)
    HSW(P4.y) HSW(P4.w) HSW(P5.y) HSW(P5.w)
    HSW(P6.y) HSW(P6.w) HSW(P7.y) HSW(P7.w)

    // CX odds (5,6)(7,8)(9,10)(11,12)(13,14)
    LANE_CX(3, ((lane >> 4) & 1) != 0)                    // (5,6)
    LANE_CX(1, ((lane >> 2) & 1) != 0)                    // (7,8) [DPP]
    { const bool pred = (lane & 1) != 0;                  // (9,10): ctrl lane0, tgt g2
      CSWP(P0, P4) CSWP(P1, P5) CSWP(P2, P6) CSWP(P3, P7) }
    SW4(P2, P3) SW4(P6, P7)                               // (11,12): ctrl g1, tgt g0
    SWZW(P0) SWZW(P1) SWZW(P2) SWZW(P3)                   // (13,14): ctrl j1, tgt j0
    SWZW(P4) SWZW(P5) SWZW(P6) SWZW(P7)

    // RY q5..q15 (q4 deferred until after CX(3,4))
    LANE_RY(4, 5)
    LANE_RY(3, 6)
    LANE_RY(2, 7)
    LANE_RY(1, 8)   // [DPP]
    LANE_RY(0, 9)   // [DPP]
    LOC_RY(10, PRY4H(P0,P4) PRY4H(P1,P5) PRY4H(P2,P6) PRY4H(P3,P7))
    LOC_RY(11, PRY4H(P0,P2) PRY4H(P1,P3) PRY4H(P4,P6) PRY4H(P5,P7))
    LOC_RY(12, PRY4H(P0,P1) PRY4H(P2,P3) PRY4H(P4,P5) PRY4H(P6,P7))
    LOC_RY(13, PRYH(P0.x,P0.z) PRYH(P0.y,P0.w) PRYH(P1.x,P1.z) PRYH(P1.y,P1.w)
               PRYH(P2.x,P2.z) PRYH(P2.y,P2.w) PRYH(P3.x,P3.z) PRYH(P3.y,P3.w)
               PRYH(P4.x,P4.z) PRYH(P4.y,P4.w) PRYH(P5.x,P5.z) PRYH(P5.y,P5.w)
               PRYH(P6.x,P6.z) PRYH(P6.y,P6.w) PRYH(P7.x,P7.z) PRYH(P7.y,P7.w))
    LOC_RY(14, PRYH(P0.x,P0.y) PRYH(P0.z,P0.w) PRYH(P1.x,P1.y) PRYH(P1.z,P1.w)
               PRYH(P2.x,P2.y) PRYH(P2.z,P2.w) PRYH(P3.x,P3.y) PRYH(P3.z,P3.w)
               PRYH(P4.x,P4.y) PRYH(P4.z,P4.w) PRYH(P5.x,P5.y) PRYH(P5.z,P5.w)
               PRYH(P6.x,P6.y) PRYH(P6.z,P6.w) PRYH(P7.x,P7.y) PRYH(P7.z,P7.w))
    LOC_RY15(15)

    // ===== transposed phase: q0->g2, q1->g1, q2->g0, q3->j1 =====
    TRANSPOSE()
    SW4(P4, P6) SW4(P5, P7)                               // CX(0,1): ctrl g2, tgt g1
    SWXZYW(P1) SWXZYW(P3) SWXZYW(P5) SWXZYW(P7)           // CX(2,3): ctrl g0, tgt j1
    SW4(P2, P3) SW4(P6, P7)                               // CX(1,2): ctrl g1, tgt g0
    X32C(P0.z) X32C(P0.w) X32C(P1.z) X32C(P1.w)           // CX(3,4): ctrl j1, tgt lane5
    X32C(P2.z) X32C(P2.w) X32C(P3.z) X32C(P3.w)
    X32C(P4.z) X32C(P4.w) X32C(P5.z) X32C(P5.w)
    X32C(P6.z) X32C(P6.w) X32C(P7.z) X32C(P7.w)
    LOC_RY(0, PRY4H(P0,P4) PRY4H(P1,P5) PRY4H(P2,P6) PRY4H(P3,P7))   // RY(0): g2
    LOC_RY(1, PRY4H(P0,P2) PRY4H(P1,P3) PRY4H(P4,P6) PRY4H(P5,P7))   // RY(1): g1
    LOC_RY(2, PRY4H(P0,P1) PRY4H(P2,P3) PRY4H(P4,P5) PRY4H(P6,P7))   // RY(2): g0
    LOC_RY(3, PRYH(P0.x,P0.z) PRYH(P0.y,P0.w) PRYH(P1.x,P1.z) PRYH(P1.y,P1.w)  // RY(3): j1
              PRYH(P2.x,P2.z) PRYH(P2.y,P2.w) PRYH(P3.x,P3.z) PRYH(P3.y,P3.w)
              PRYH(P4.x,P4.z) PRYH(P4.y,P4.w) PRYH(P5.x,P5.z) PRYH(P5.y,P5.w)
              PRYH(P6.x,P6.z) PRYH(P6.y,P6.w) PRYH(P7.x,P7.z) PRYH(P7.y,P7.w))
    LANE_RY(5, 4)                                         // RY(4): lane5 (after CX(3,4))
    TRANSPOSE()
  }

  // ---------- measurement (f32): <Z_q>, q = 0..9 ----------
  float tot = 0.f;
  SQP(P0) SQP(P1) SQP(P2) SQP(P3) SQP(P4) SQP(P5) SQP(P6) SQP(P7)

  float r0 = tot;
  float r1 = ((lane >> 5) & 1) ? -tot : tot;
  float r2 = ((lane >> 4) & 1) ? -tot : tot;
  float r3 = ((lane >> 3) & 1) ? -tot : tot;
  float r4 = ((lane >> 2) & 1) ? -tot : tot;
  float r5 = ((lane >> 1) & 1) ? -tot : tot;
  float r6 = ( lane       & 1) ? -tot : tot;
  RED(r0) RED(r1) RED(r2) RED(r3) RED(r4) RED(r5) RED(r6)

  __syncthreads();  // done with gate LDS usage
  if (lane == 0) {
    const int base = (tid >> 6) * 8;
    lds[base + 0] = r0; lds[base + 1] = r1; lds[base + 2] = r2; lds[base + 3] = r3;
    lds[base + 4] = r4; lds[base + 5] = r5; lds[base + 6] = r6;
  }
  __syncthreads();

  if (tid < NCLASS) {
    float acc = 0.f;
    if (tid < 4) {  // class qubit q=tid on wave bit (3-tid)
#pragma unroll
      for (int wv = 0; wv < 16; ++wv) {
        float v = lds[wv * 8];
        acc += (((wv >> (3 - tid)) & 1) != 0) ? -v : v;
      }
    } else {        // class qubit q=tid, signed partial at slot (tid-3)
#pragma unroll
      for (int wv = 0; wv < 16; ++wv) acc += lds[wv * 8 + (tid - 3)];
    }
    out[b * NCLASS + tid] = acc;
  }
}

extern "C" void kernel_launch(void* const* d_in, const int* in_sizes, int n_in,
                              void* d_out, int out_size, void* d_ws, size_t ws_size,
                              hipStream_t stream) {
  (void)in_sizes; (void)n_in; (void)d_ws; (void)ws_size; (void)out_size;
  const float* x = (const float*)d_in[0];
  const float* w = (const float*)d_in[1];
  float* out = (float*)d_out;

  // 128 KB dynamic LDS (gfx950 has 160 KB/CU) — opt in every call (idempotent).
  hipFuncSetAttribute(reinterpret_cast<const void*>(vqc_kernel),
                      hipFuncAttributeMaxDynamicSharedMemorySize, 131072);

  vqc_kernel<<<BATCH, 1024, 131072, stream>>>(x, w, out);
}